// Round 4
// baseline (662.380 us; speedup 1.0000x reference)
//
#include <hip/hip_runtime.h>
#include <hip/hip_bf16.h>

// ReprogrammingLayer: q=QWq+bq; k=KsWk+bk; v=VsWv+bv (8 heads, E=128);
// A=softmax(qk^T/sqrt(512)); out=(Av)Wo+bo.
// I/O FP32 (reference dtypes); internal bf16 MFMA + fp32 accum (2% threshold).
// scale*log2(e) is folded into Wq/bq so attention softmax runs in base-2.
//
// ws layout (bf16 elems, peak 33M = 66MB):
//   qb[8M]@0 | kb[2M]@8M | vtb[2M]@10M | at[8M]@12M
//   WqT[1M]@20M | WkT[4M]@21M | WvT[4M]@25M | WoT[4M]@29M

typedef __bf16 bf16x8 __attribute__((ext_vector_type(8)));
typedef float  f32x4  __attribute__((ext_vector_type(4)));

union V16 { uint4 u; bf16x8 v; };
__device__ __forceinline__ bf16x8 ld16v(const void* p) {
  V16 t; t.u = *(const uint4*)p; return t.v;
}
__device__ __forceinline__ uint4 pack8(float4 a, float4 b) {
  V16 t;
  t.v[0] = (__bf16)a.x; t.v[1] = (__bf16)a.y; t.v[2] = (__bf16)a.z; t.v[3] = (__bf16)a.w;
  t.v[4] = (__bf16)b.x; t.v[5] = (__bf16)b.y; t.v[6] = (__bf16)b.z; t.v[7] = (__bf16)b.w;
  return t.u;
}
// async global->LDS DMA, 16B/lane; LDS dest = wave-uniform base + lane*16
__device__ __forceinline__ void dma16(const void* g, void* l) {
  __builtin_amdgcn_global_load_lds(
      (const __attribute__((address_space(1))) unsigned int*)g,
      (__attribute__((address_space(3))) unsigned int*)l, 16, 0, 0);
}
// raw v_exp_f32 (D = 2^S0); s_nop covers the trans->use wait state the
// compiler can't see through the asm.
__device__ __forceinline__ float exp2_fast(float x) {
  float r;
  asm("v_exp_f32 %0, %1\n\ts_nop 1" : "=v"(r) : "v"(x));
  return r;
}
// XOR-swizzled 16B-chunk index for a 128x32 bf16 tile (4 chunks/row).
__device__ __forceinline__ int chunk_of(int row, int gc) {
  return row * 4 + (gc ^ ((row >> 1) & 3));
}

// -------- weight transpose+convert+scale: W[K][N] fp32 -> Wt[N][K] bf16 ----
__global__ __launch_bounds__(256) void transpose_k(const float* __restrict__ W,
                                                   __bf16* __restrict__ Wt, int K, int N,
                                                   float scale) {
  __shared__ __bf16 t[32][33];
  int tx = threadIdx.x & 31, ty = threadIdx.x >> 5;
  int n0 = blockIdx.x * 32, k0 = blockIdx.y * 32;
#pragma unroll
  for (int r = 0; r < 32; r += 8)
    t[ty + r][tx] = (__bf16)(W[(size_t)(k0 + ty + r) * N + n0 + tx] * scale);
  __syncthreads();
#pragma unroll
  for (int r = 0; r < 32; r += 8) Wt[(size_t)(n0 + ty + r) * K + k0 + tx] = t[tx][ty + r];
}

// -------- GEMM core: C = A[M,K] @ Bt[N,K]^T + bscale*bias --------
// 128x128 tile, BK=32, 4 waves 2x2, 4x4 16x16x32 bf16 mfma frags.
// Round-4: depth-1 software pipeline (attn_k pattern, T3/T4): double-buffered
// staging, prefetch tile t+1 during tile t, counted vmcnt (never 0 in-loop).
// Previously each k-iter drained vmcnt(0) at the barrier -> at 1 block/CU a
// k-iter cost ~3000 cy of exposed global->LDS latency (gemm_kv round-2:
// 1.23us/iter; round-3 gemm_qkv tail identical).
//  * bf16 A: A,B both via dma16 into double buffers; vmcnt(4).
//  * fp32 A: A global->regs issued one iter EARLY (T14 async-split), packed
//    to bf16 + ds_write into a SINGLE As buffer at top of iter (safe: last
//    reads of As drained by lgkm0+barrier); B via dma16 double-buffered;
//    vmcnt(6)+lgkm(0) keeps t+1's 4 A-loads + 2 B-dma in flight across the
//    compute barrier.
template <typename AT, typename CT>
__device__ __forceinline__ void gemm_core(__bf16* As0, __bf16* As1,
                                          __bf16* Bs0, __bf16* Bs1,
                                          const AT* __restrict__ A,
                                          const __bf16* __restrict__ Bt,
                                          const float* __restrict__ bias,
                                          CT* __restrict__ C,
                                          int M, int N, int K, int lda, int trans,
                                          int m0, int n0, float bscale) {
  const int tid = threadIdx.x;
  const int lane = tid & 63, wave = tid >> 6;
  const int g = lane >> 4, l16 = lane & 15;
  const int wr = wave >> 1, wc = wave & 1;
  int aoff[4], boff[4];
#pragma unroll
  for (int mf = 0; mf < 4; mf++) aoff[mf] = chunk_of(wr * 64 + mf * 16 + l16, g) * 8;
#pragma unroll
  for (int nf = 0; nf < 4; nf++) boff[nf] = chunk_of(wc * 64 + nf * 16 + l16, g) * 8;

  // staging geometry (identical swizzle for A and B tiles)
  const int cA = wave * 128 + lane;           // chunk ids: cA, cA+64 (dma A / B)
  const int p0 = tid, p1 = tid + 256;         // chunk ids (fp32 reg-staged A)

  f32x4 acc[4][4] = {};
  float4 a0l, a0h, a1l, a1h;                  // fp32-A in-flight regs (tile t)

  // ---- prologue: stage tile 0 ----
  if constexpr (sizeof(AT) == 2) {
#pragma unroll
    for (int rnd = 0; rnd < 2; rnd++) {
      int c = cA + rnd * 64;
      int row = c >> 2, gc = (c & 3) ^ ((row >> 1) & 3);
      dma16((const __bf16*)A + (size_t)(m0 + row) * lda + gc * 8,
            As0 + (wave * 128 + rnd * 64) * 8);
    }
  } else {
    { int row = p0 >> 2, gc = (p0 & 3) ^ ((row >> 1) & 3);
      const float* ap = (const float*)A + (size_t)(m0 + row) * lda + gc * 8;
      a0l = *(const float4*)ap; a0h = *(const float4*)(ap + 4); }
    { int row = p1 >> 2, gc = (p1 & 3) ^ ((row >> 1) & 3);
      const float* ap = (const float*)A + (size_t)(m0 + row) * lda + gc * 8;
      a1l = *(const float4*)ap; a1h = *(const float4*)(ap + 4); }
  }
#pragma unroll
  for (int rnd = 0; rnd < 2; rnd++) {
    int c = cA + rnd * 64;
    int row = c >> 2, gc = (c & 3) ^ ((row >> 1) & 3);
    dma16(Bt + (size_t)(n0 + row) * (size_t)K + gc * 8,
          Bs0 + (wave * 128 + rnd * 64) * 8);
  }

  for (int k0 = 0, t = 0; k0 < K; k0 += 32, t++) {
    __bf16* Ac = (t & 1) ? As1 : As0;
    __bf16* An = (t & 1) ? As0 : As1;
    __bf16* Bc = (t & 1) ? Bs1 : Bs0;
    __bf16* Bn = (t & 1) ? Bs0 : Bs1;
    if constexpr (sizeof(AT) != 2) Ac = As0;    // single A buffer (reg dbuf)
    const int kn = (k0 + 32 < K) ? k0 + 32 : 0; // wrap: redundant prefetch, keeps counts uniform
    // (A) all waves done reading the buffers we're about to overwrite
    asm volatile("s_waitcnt lgkmcnt(0)" ::: "memory");
    __builtin_amdgcn_s_barrier();
    __builtin_amdgcn_sched_barrier(0);
    if constexpr (sizeof(AT) == 2) {
      // prefetch t+1 (4 dma), then wait tile t's 4 dma (in flight: t+1's 4)
#pragma unroll
      for (int rnd = 0; rnd < 2; rnd++) {
        int c = cA + rnd * 64;
        int row = c >> 2, gc = (c & 3) ^ ((row >> 1) & 3);
        dma16((const __bf16*)A + (size_t)(m0 + row) * lda + kn + gc * 8,
              An + (wave * 128 + rnd * 64) * 8);
      }
#pragma unroll
      for (int rnd = 0; rnd < 2; rnd++) {
        int c = cA + rnd * 64;
        int row = c >> 2, gc = (c & 3) ^ ((row >> 1) & 3);
        dma16(Bt + (size_t)(n0 + row) * (size_t)K + kn + gc * 8,
              Bn + (wave * 128 + rnd * 64) * 8);
      }
      __builtin_amdgcn_sched_barrier(0);
      asm volatile("s_waitcnt vmcnt(4)" ::: "memory");
    } else {
      // commit A(t) regs -> LDS (compiler auto-waits the t-loads)
      *(uint4*)(Ac + p0 * 8) = pack8(a0l, a0h);
      *(uint4*)(Ac + p1 * 8) = pack8(a1l, a1h);
      __builtin_amdgcn_sched_barrier(0);
      // prefetch t+1: 4 A-loads + 2 B-dma
      { int row = p0 >> 2, gc = (p0 & 3) ^ ((row >> 1) & 3);
        const float* ap = (const float*)A + (size_t)(m0 + row) * lda + kn + gc * 8;
        a0l = *(const float4*)ap; a0h = *(const float4*)(ap + 4); }
      { int row = p1 >> 2, gc = (p1 & 3) ^ ((row >> 1) & 3);
        const float* ap = (const float*)A + (size_t)(m0 + row) * lda + kn + gc * 8;
        a1l = *(const float4*)ap; a1h = *(const float4*)(ap + 4); }
#pragma unroll
      for (int rnd = 0; rnd < 2; rnd++) {
        int c = cA + rnd * 64;
        int row = c >> 2, gc = (c & 3) ^ ((row >> 1) & 3);
        dma16(Bt + (size_t)(n0 + row) * (size_t)K + kn + gc * 8,
              Bn + (wave * 128 + rnd * 64) * 8);
      }
      __builtin_amdgcn_sched_barrier(0);
      // B(t) done (6 newer vmem ops stay in flight); own ds_writes visible
      asm volatile("s_waitcnt vmcnt(6) lgkmcnt(0)" ::: "memory");
    }
    __builtin_amdgcn_s_barrier();
    __builtin_amdgcn_sched_barrier(0);

    bf16x8 af[4], bff[4];
#pragma unroll
    for (int mf = 0; mf < 4; mf++) af[mf]  = ld16v(Ac + aoff[mf]);
#pragma unroll
    for (int nf = 0; nf < 4; nf++) bff[nf] = ld16v(Bc + boff[nf]);
    __builtin_amdgcn_s_setprio(1);
#pragma unroll
    for (int mf = 0; mf < 4; mf++)
#pragma unroll
      for (int nf = 0; nf < 4; nf++)
        acc[mf][nf] = __builtin_amdgcn_mfma_f32_16x16x32_bf16(af[mf], bff[nf], acc[mf][nf], 0, 0, 0);
    __builtin_amdgcn_s_setprio(0);
  }
#pragma unroll
  for (int nf = 0; nf < 4; nf++) {
    int col = n0 + wc * 64 + nf * 16 + l16;
    float bv = bias[col] * bscale;
#pragma unroll
    for (int mf = 0; mf < 4; mf++) {
      int rowb = m0 + wr * 64 + mf * 16 + g * 4;
      if constexpr (sizeof(CT) == 2) {
        if (trans) {
          union { __bf16 h[4]; uint2 u; } pk;
#pragma unroll
          for (int r = 0; r < 4; r++) pk.h[r] = (__bf16)(acc[mf][nf][r] + bv);
          *(uint2*)&((__bf16*)C)[(size_t)col * M + rowb] = pk.u;   // C^T[n][m]
        } else {
#pragma unroll
          for (int r = 0; r < 4; r++)
            ((__bf16*)C)[(size_t)(rowb + r) * N + col] = (__bf16)(acc[mf][nf][r] + bv);
        }
      } else {
#pragma unroll
        for (int r = 0; r < 4; r++)
          ((float*)C)[(size_t)(rowb + r) * N + col] = acc[mf][nf][r] + bv;
      }
    }
  }
}

// Merged QKV projection, 768 blocks (3/CU co-resident):
//   bid [0,512):   q = Q @ WqT + bq*qscale   (8192x1024, K=1024)
//   bid [512,640): k = Ksr @ WkT + bk        (2048x1024, K=4096)
//   bid [640,768): vT = (Vsr @ WvT + bv)^T   (2048x1024, K=4096, trans)
// fp32-A core: single As (8KB) + double Bs (16KB) = 24KB LDS.
__global__ __launch_bounds__(256) void gemm_qkv(
    const float* __restrict__ Q,   const __bf16* __restrict__ WqT, const float* __restrict__ bq, __bf16* __restrict__ qb, float qscale,
    const float* __restrict__ Ksr, const __bf16* __restrict__ WkT, const float* __restrict__ bk, __bf16* __restrict__ kb,
    const float* __restrict__ Vsr, const __bf16* __restrict__ WvT, const float* __restrict__ bv, __bf16* __restrict__ vtb) {
  __shared__ __align__(16) __bf16 As[128 * 32];
  __shared__ __align__(16) __bf16 Bs[2][128 * 32];
  const int bid = blockIdx.x;
  if (bid < 512) {
    gemm_core<float, __bf16>(As, As, Bs[0], Bs[1], Q, WqT, bq, qb, 8192, 1024, 1024, 1024, 0,
                             (bid & 63) * 128, (bid >> 6) * 128, qscale);
  } else if (bid < 640) {
    const int b = bid - 512;
    gemm_core<float, __bf16>(As, As, Bs[0], Bs[1], Ksr, WkT, bk, kb, 2048, 1024, 4096, 4096, 0,
                             (b & 15) * 128, (b >> 4) * 128, 1.0f);
  } else {
    const int b = bid - 640;
    gemm_core<float, __bf16>(As, As, Bs[0], Bs[1], Vsr, WvT, bv, vtb, 2048, 1024, 4096, 4096, 1,
                             (b & 15) * 128, (b >> 4) * 128, 1.0f);
  }
}

__global__ __launch_bounds__(256) void gemm_b_f(const __bf16* __restrict__ A,
                                                const __bf16* __restrict__ Bt,
                                                const float* __restrict__ bias,
                                                float* __restrict__ C,
                                                int M, int N, int K, int lda, int trans) {
  __shared__ __align__(16) __bf16 As[2][128 * 32];
  __shared__ __align__(16) __bf16 Bs[2][128 * 32];
  gemm_core<__bf16, float>(As[0], As[1], Bs[0], Bs[1], A, Bt, bias, C, M, N, K, lda, trans,
                           blockIdx.x * 128, blockIdx.y * 128, 1.0f);
}

// -------- flash attention --------
// QBLK=128, 8 waves x 16 q-rows, grid 64x8 = 512 blocks (2/CU, 16 w/CU).
// Double-buffered K/V tiles + one-tile prefetch, counted vmcnt (T4):
//   lgkmcnt(0)+barrier ; issue DMA(t+1)->buf^1 ; vmcnt(4)+barrier ; compute
// P tile [128][64] XOR-chunk-swizzled, wave-private rows.
// LDS = 2*16K (K) + 2*16K (V) + 16K (P) = 80KB -> 2 blocks/CU.
// exp2 via raw v_exp_f32 asm; scale*log2e pre-folded into q.
__global__ __launch_bounds__(512, 4) void attn_k(const __bf16* __restrict__ q,
                                                 const __bf16* __restrict__ k,
                                                 const __bf16* __restrict__ vt,
                                                 __bf16* __restrict__ o) {
  __shared__ __align__(16) __bf16 ks[2][64 * 128];   // K tile [s][e], swizzled chunks
  __shared__ __align__(16) __bf16 vs[2][128 * 64];   // V^T tile [e][s], swizzled chunks
  __shared__ __align__(16) __bf16 ps[128 * 64];      // P tile [q][s], swizzled chunks
  const int tid = threadIdx.x, lane = tid & 63, wave = tid >> 6;
  const int g = lane >> 4, l16 = lane & 15;
  const int h = blockIdx.y, q0 = blockIdx.x * 128;

  const __bf16* kbase = k + (size_t)h * 128;
  const __bf16* vbase = vt + (size_t)(h * 128) * 2048;

  bf16x8 qf[4];                    // Q rows q0+wave*16+l16 (scale pre-folded)
#pragma unroll
  for (int kk = 0; kk < 4; kk++)
    qf[kk] = ld16v(q + (size_t)(q0 + wave * 16 + l16) * 1024 + h * 128 + kk * 32 + g * 8);

  f32x4 accO[8] = {};
  float m_i[4], l_i[4];
#pragma unroll
  for (int r = 0; r < 4; r++) { m_i[r] = -1e30f; l_i[r] = 0.f; }

  // prologue: stage tile 0 into buf 0 (4 DMA issues/wave)
  {
#pragma unroll
    for (int i = 0; i < 2; i++) {
      int c = wave * 128 + i * 64 + lane;
      int row = c >> 4, gc = (c & 15) ^ (row & 7);
      dma16(kbase + (size_t)row * 1024 + gc * 8, &ks[0][(wave * 128 + i * 64) * 8]);
    }
#pragma unroll
    for (int i = 0; i < 2; i++) {
      int c = wave * 128 + i * 64 + lane;
      int row = c >> 3, cc = (c & 7) ^ (row & 7);
      dma16(vbase + (size_t)row * 2048 + cc * 8, &vs[0][(wave * 128 + i * 64) * 8]);
    }
  }

  for (int t = 0; t < 32; t++) {
    const int cur = t & 1;
    // (A) all waves done reading buf^1 (prev tile's compute) -> safe to DMA
    asm volatile("s_waitcnt lgkmcnt(0)" ::: "memory");
    __builtin_amdgcn_s_barrier();
    __builtin_amdgcn_sched_barrier(0);
    {                               // prefetch tile t+1 into buf^1 (wraps at end)
      const int sn = ((t + 1) & 31) * 64;
#pragma unroll
      for (int i = 0; i < 2; i++) {
        int c = wave * 128 + i * 64 + lane;
        int row = c >> 4, gc = (c & 15) ^ (row & 7);
        dma16(kbase + (size_t)(sn + row) * 1024 + gc * 8,
              &ks[cur ^ 1][(wave * 128 + i * 64) * 8]);
      }
#pragma unroll
      for (int i = 0; i < 2; i++) {
        int c = wave * 128 + i * 64 + lane;
        int row = c >> 3, cc = (c & 7) ^ (row & 7);
        dma16(vbase + (size_t)row * 2048 + sn + cc * 8,
              &vs[cur ^ 1][(wave * 128 + i * 64) * 8]);
      }
    }
    // (B) tile t staged by ALL waves (own vmcnt(4) + barrier); prefetch stays
    // in flight across the barrier (counted vmcnt, never 0 in-loop).
    asm volatile("s_waitcnt vmcnt(4)" ::: "memory");
    __builtin_amdgcn_s_barrier();
    __builtin_amdgcn_sched_barrier(0);

    f32x4 sc[4] = {};
    __builtin_amdgcn_s_setprio(1);
#pragma unroll
    for (int kk = 0; kk < 4; kk++) {  // QK^T, contract e=128
      bf16x8 kf[4];
#pragma unroll
      for (int nf = 0; nf < 4; nf++) {
        int row = nf * 16 + l16;
        kf[nf] = ld16v(&ks[cur][(row * 16 + ((kk * 4 + g) ^ (row & 7))) * 8]);
      }
#pragma unroll
      for (int nf = 0; nf < 4; nf++)
        sc[nf] = __builtin_amdgcn_mfma_f32_16x16x32_bf16(qf[kk], kf[nf], sc[nf], 0, 0, 0);
    }
    __builtin_amdgcn_s_setprio(0);

    // online softmax, base-2 domain; row g*4+r lives in the 16 lanes of group g
#pragma unroll
    for (int r = 0; r < 4; r++) {
      float mx = fmaxf(fmaxf(sc[0][r], sc[1][r]), fmaxf(sc[2][r], sc[3][r]));
#pragma unroll
      for (int off = 1; off < 16; off <<= 1) mx = fmaxf(mx, __shfl_xor(mx, off));
      float mn = fmaxf(m_i[r], mx);
      float alpha = exp2_fast(m_i[r] - mn);
      float rs = 0.f;
#pragma unroll
      for (int nf = 0; nf < 4; nf++) {
        float p = exp2_fast(sc[nf][r] - mn);
        sc[nf][r] = p;
        rs += p;
      }
#pragma unroll
      for (int off = 1; off < 16; off <<= 1) rs += __shfl_xor(rs, off);
      m_i[r] = mn;
      l_i[r] = l_i[r] * alpha + rs;
#pragma unroll
      for (int ef = 0; ef < 8; ef++) accO[ef][r] *= alpha;
    }

    // P write: wave-private rows, swizzled chunks; same-wave DS order suffices
#pragma unroll
    for (int nf = 0; nf < 4; nf++)
#pragma unroll
      for (int r = 0; r < 4; r++) {
        int prow = wave * 16 + g * 4 + r;
        int cc = nf * 2 + (l16 >> 3);
        ps[(prow * 8 + (cc ^ (prow & 7))) * 8 + (l16 & 7)] = (__bf16)sc[nf][r];
      }

    __builtin_amdgcn_s_setprio(1);
#pragma unroll
    for (int kk = 0; kk < 2; kk++) {   // PV, contract s=64
      int prow = wave * 16 + l16;
      bf16x8 pf = ld16v(&ps[(prow * 8 + ((kk * 4 + g) ^ (prow & 7))) * 8]);
#pragma unroll
      for (int ef = 0; ef < 8; ef++) {
        int vrow = ef * 16 + l16;
        bf16x8 vf = ld16v(&vs[cur][(vrow * 8 + ((kk * 4 + g) ^ (vrow & 7))) * 8]);
        accO[ef] = __builtin_amdgcn_mfma_f32_16x16x32_bf16(pf, vf, accO[ef], 0, 0, 0);
      }
    }
    __builtin_amdgcn_s_setprio(0);
  }

  float inv[4];
#pragma unroll
  for (int r = 0; r < 4; r++) inv[r] = 1.0f / l_i[r];
#pragma unroll
  for (int ef = 0; ef < 8; ef++)
#pragma unroll
    for (int r = 0; r < 4; r++) {
      int row = q0 + wave * 16 + g * 4 + r;
      o[(size_t)row * 1024 + h * 128 + ef * 16 + l16] = (__bf16)(accO[ef][r] * inv[r]);
    }
}

extern "C" void kernel_launch(void* const* d_in, const int* in_sizes, int n_in,
                              void* d_out, int out_size, void* d_ws, size_t ws_size,
                              hipStream_t stream) {
  const float* Q   = (const float*)d_in[0];
  const float* Ksr = (const float*)d_in[1];
  const float* Vsr = (const float*)d_in[2];
  const float* Wq  = (const float*)d_in[3];
  const float* bq  = (const float*)d_in[4];
  const float* Wk  = (const float*)d_in[5];
  const float* bk  = (const float*)d_in[6];
  const float* Wv  = (const float*)d_in[7];
  const float* bv  = (const float*)d_in[8];
  const float* Wo  = (const float*)d_in[9];
  const float* bo  = (const float*)d_in[10];
  __bf16* ws = (__bf16*)d_ws;
  const size_t MB = 1024 * 1024;
  __bf16* qb  = ws;             // [8192,1024] (pre-scaled by qscale)
  __bf16* kb  = ws + 8  * MB;   // [2048,1024]
  __bf16* vtb = ws + 10 * MB;   // [1024,2048] = v^T
  __bf16* at  = ws + 12 * MB;   // [8192,1024]
  __bf16* WqT = ws + 20 * MB;   // [1024,1024]
  __bf16* WkT = ws + 21 * MB;   // [1024,4096]
  __bf16* WvT = ws + 25 * MB;   // [1024,4096]
  __bf16* WoT = ws + 29 * MB;   // [4096,1024]

  // 1/sqrt(512) * log2(e): softmax computed as 2^x in attn_k
  const float qscale = 0.044194173824159216f * 1.4426950408889634f;

  transpose_k<<<dim3(32, 32),  256, 0, stream>>>(Wq, WqT, 1024, 1024, qscale);
  transpose_k<<<dim3(32, 128), 256, 0, stream>>>(Wk, WkT, 4096, 1024, 1.0f);
  transpose_k<<<dim3(32, 128), 256, 0, stream>>>(Wv, WvT, 4096, 1024, 1.0f);
  transpose_k<<<dim3(128, 32), 256, 0, stream>>>(Wo, WoT, 1024, 4096, 1.0f);

  gemm_qkv<<<dim3(768), 256, 0, stream>>>(Q, WqT, bq, qb, qscale,
                                          Ksr, WkT, bk, kb,
                                          Vsr, WvT, bv, vtb);
  attn_k<<<dim3(64, 8), 512, 0, stream>>>(qb, kb, vtb, at);
  gemm_b_f<<<dim3(64, 32), 256, 0, stream>>>(at, WoT, bo, (float*)d_out, 8192, 4096, 1024, 1024, 0);
}

// Round 5
// 636.604 us; speedup vs baseline: 1.0405x; 1.0405x over previous
//
#include <hip/hip_runtime.h>
#include <hip/hip_bf16.h>

// ReprogrammingLayer: q=QWq+bq; k=KsWk+bk; v=VsWv+bv (8 heads, E=128);
// A=softmax(qk^T/sqrt(512)); out=(Av)Wo+bo.
// I/O FP32 (reference dtypes); internal bf16 MFMA + fp32 accum (2% threshold).
// scale*log2(e) is folded into Wq/bq so attention softmax runs in base-2.
//
// Round-5: uniform-duration QKV grid. KV projections split-K=2 (64 iters,
// bf16 partials, bias in group 0), Q-blocks do two n-tiles (64 iters) ->
// 768 equal blocks (3/CU, no tail; round-4's tail ran 96/128 iters at
// 1 block/CU). gemm_core reverted to the proven simple 2-barrier m97
// structure (round-4's depth-1 pipeline + sched_barriers REGRESSED:
// MfmaUtil 9.7->9.1, VALUBusy 16->12.8).
//
// ws layout (bf16 elems, 33M = 66MB):
//   qb[8M]@0 (q; attn writes output IN-PLACE) | kb[2M]@8M | vtb[2M]@10M
//   kp0[2M]@12M | kp1[2M]@14M | vp0[2M]@16M | vp1[2M]@18M   (split-K partials)
//   WqT[1M]@20M | WkT[4M]@21M | WvT[4M]@25M | WoT[4M]@29M

typedef __bf16 bf16x8 __attribute__((ext_vector_type(8)));
typedef float  f32x4  __attribute__((ext_vector_type(4)));

union V16 { uint4 u; bf16x8 v; };
__device__ __forceinline__ bf16x8 ld16v(const void* p) {
  V16 t; t.u = *(const uint4*)p; return t.v;
}
__device__ __forceinline__ uint4 pack8(float4 a, float4 b) {
  V16 t;
  t.v[0] = (__bf16)a.x; t.v[1] = (__bf16)a.y; t.v[2] = (__bf16)a.z; t.v[3] = (__bf16)a.w;
  t.v[4] = (__bf16)b.x; t.v[5] = (__bf16)b.y; t.v[6] = (__bf16)b.z; t.v[7] = (__bf16)b.w;
  return t.u;
}
// async global->LDS DMA, 16B/lane; LDS dest = wave-uniform base + lane*16
__device__ __forceinline__ void dma16(const void* g, void* l) {
  __builtin_amdgcn_global_load_lds(
      (const __attribute__((address_space(1))) unsigned int*)g,
      (__attribute__((address_space(3))) unsigned int*)l, 16, 0, 0);
}
// raw v_exp_f32 (D = 2^S0); s_nop covers the trans->use wait state.
__device__ __forceinline__ float exp2_fast(float x) {
  float r;
  asm("v_exp_f32 %0, %1\n\ts_nop 1" : "=v"(r) : "v"(x));
  return r;
}
// XOR-swizzled 16B-chunk index for a 128x32 bf16 tile (4 chunks/row).
__device__ __forceinline__ int chunk_of(int row, int gc) {
  return row * 4 + (gc ^ ((row >> 1) & 3));
}

// -------- weight transpose+convert+scale: W[K][N] fp32 -> Wt[N][K] bf16 ----
__global__ __launch_bounds__(256) void transpose_k(const float* __restrict__ W,
                                                   __bf16* __restrict__ Wt, int K, int N,
                                                   float scale) {
  __shared__ __bf16 t[32][33];
  int tx = threadIdx.x & 31, ty = threadIdx.x >> 5;
  int n0 = blockIdx.x * 32, k0 = blockIdx.y * 32;
#pragma unroll
  for (int r = 0; r < 32; r += 8)
    t[ty + r][tx] = (__bf16)(W[(size_t)(k0 + ty + r) * N + n0 + tx] * scale);
  __syncthreads();
#pragma unroll
  for (int r = 0; r < 32; r += 8) Wt[(size_t)(n0 + ty + r) * K + k0 + tx] = t[tx][ty + r];
}

// -------- GEMM core: C = A[M,K] @ Bt[N,K(ldb)]^T + bscale*bias --------
// 128x128 tile, BK=32, 4 waves 2x2, 4x4 16x16x32 bf16 mfma frags.
// Simple m97-style 2-barrier loop (relies on >=3 blocks/CU co-residency for
// latency hiding — guaranteed by the uniform 768-block grid).
template <typename AT, typename CT>
__device__ __forceinline__ void gemm_core(__bf16* As, __bf16* Bs,
                                          const AT* __restrict__ A,
                                          const __bf16* __restrict__ Bt,
                                          const float* __restrict__ bias,
                                          CT* __restrict__ C,
                                          int M, int N, int K, int lda, int ldb, int trans,
                                          int m0, int n0, float bscale) {
  const int tid = threadIdx.x;
  const int lane = tid & 63, wave = tid >> 6;
  const int g = lane >> 4, l16 = lane & 15;
  const int wr = wave >> 1, wc = wave & 1;
  int aoff[4], boff[4];
#pragma unroll
  for (int mf = 0; mf < 4; mf++) aoff[mf] = chunk_of(wr * 64 + mf * 16 + l16, g) * 8;
#pragma unroll
  for (int nf = 0; nf < 4; nf++) boff[nf] = chunk_of(wc * 64 + nf * 16 + l16, g) * 8;

  f32x4 acc[4][4] = {};
  for (int k0 = 0; k0 < K; k0 += 32) {
    __syncthreads();
    if constexpr (sizeof(AT) == 2) {       // bf16 A: DMA, 2 issues/wave
#pragma unroll
      for (int rnd = 0; rnd < 2; rnd++) {
        int cstart = wave * 128 + rnd * 64;
        int p = cstart + lane;
        int row = p >> 2, gc = (p & 3) ^ ((row >> 1) & 3);
        dma16((const __bf16*)A + (size_t)(m0 + row) * lda + k0 + gc * 8,
              As + (size_t)cstart * 8);
      }
    } else {                               // fp32 A: load+convert
#pragma unroll
      for (int i = 0; i < 2; i++) {
        int p = tid + i * 256;
        int row = p >> 2, gc = (p & 3) ^ ((row >> 1) & 3);
        const float* ap = (const float*)A + (size_t)(m0 + row) * lda + k0 + gc * 8;
        float4 f0 = *(const float4*)ap;
        float4 f1 = *(const float4*)(ap + 4);
        *(uint4*)(As + p * 8) = pack8(f0, f1);
      }
    }
#pragma unroll
    for (int rnd = 0; rnd < 2; rnd++) {    // B: always bf16 DMA
      int cstart = wave * 128 + rnd * 64;
      int p = cstart + lane;
      int row = p >> 2, gc = (p & 3) ^ ((row >> 1) & 3);
      dma16(Bt + (size_t)(n0 + row) * (size_t)ldb + k0 + gc * 8,
            Bs + (size_t)cstart * 8);
    }
    __syncthreads();
    bf16x8 af[4], bff[4];
#pragma unroll
    for (int mf = 0; mf < 4; mf++) af[mf]  = ld16v(As + aoff[mf]);
#pragma unroll
    for (int nf = 0; nf < 4; nf++) bff[nf] = ld16v(Bs + boff[nf]);
#pragma unroll
    for (int mf = 0; mf < 4; mf++)
#pragma unroll
      for (int nf = 0; nf < 4; nf++)
        acc[mf][nf] = __builtin_amdgcn_mfma_f32_16x16x32_bf16(af[mf], bff[nf], acc[mf][nf], 0, 0, 0);
  }
#pragma unroll
  for (int nf = 0; nf < 4; nf++) {
    int col = n0 + wc * 64 + nf * 16 + l16;
    float bv = bias[col] * bscale;
#pragma unroll
    for (int mf = 0; mf < 4; mf++) {
      int rowb = m0 + wr * 64 + mf * 16 + g * 4;
      if constexpr (sizeof(CT) == 2) {
        if (trans) {
          union { __bf16 h[4]; uint2 u; } pk;
#pragma unroll
          for (int r = 0; r < 4; r++) pk.h[r] = (__bf16)(acc[mf][nf][r] + bv);
          *(uint2*)&((__bf16*)C)[(size_t)col * M + rowb] = pk.u;   // C^T[n][m]
        } else {
#pragma unroll
          for (int r = 0; r < 4; r++)
            ((__bf16*)C)[(size_t)(rowb + r) * N + col] = (__bf16)(acc[mf][nf][r] + bv);
        }
      } else {
#pragma unroll
        for (int r = 0; r < 4; r++)
          ((float*)C)[(size_t)(rowb + r) * N + col] = acc[mf][nf][r] + bv;
      }
    }
  }
}

// Merged QKV projection, 768 UNIFORM blocks (all 64 k-iters, 3/CU):
//   bid [0,256):   q = Q @ WqT + bq*qscale — TWO n-tiles per block
//   bid [256,512): k partials: split-K=2 over K=4096, kp[g] = Ksr[:,gK] @ WkT[:,gK]^T (+bk if g==0)
//   bid [512,768): v partials, transposed output: vp[g][1024][2048]
__global__ __launch_bounds__(256) void gemm_qkv(
    const float* __restrict__ Q,   const __bf16* __restrict__ WqT, const float* __restrict__ bq, __bf16* __restrict__ qb, float qscale,
    const float* __restrict__ Ksr, const __bf16* __restrict__ WkT, const float* __restrict__ bk, __bf16* __restrict__ kp0, __bf16* __restrict__ kp1,
    const float* __restrict__ Vsr, const __bf16* __restrict__ WvT, const float* __restrict__ bv, __bf16* __restrict__ vp0, __bf16* __restrict__ vp1) {
  __shared__ __align__(16) __bf16 As[128 * 32];
  __shared__ __align__(16) __bf16 Bs[128 * 32];
  const int bid = blockIdx.x;
  if (bid < 256) {
    const int m0 = (bid & 63) * 128, n0 = (bid >> 6) * 256;
    gemm_core<float, __bf16>(As, Bs, Q, WqT, bq, qb, 8192, 1024, 1024, 1024, 1024, 0,
                             m0, n0, qscale);
    gemm_core<float, __bf16>(As, Bs, Q, WqT, bq, qb, 8192, 1024, 1024, 1024, 1024, 0,
                             m0, n0 + 128, qscale);
  } else if (bid < 512) {
    const int b = bid - 256;
    const int grp = b >> 7, bb = b & 127;          // grp: K-half
    __bf16* dst = grp ? kp1 : kp0;
    gemm_core<float, __bf16>(As, Bs, Ksr + grp * 2048, WkT + grp * 2048, bk, dst,
                             2048, 1024, 2048, 4096, 4096, 0,
                             (bb & 15) * 128, (bb >> 4) * 128, grp == 0 ? 1.0f : 0.0f);
  } else {
    const int b = bid - 512;
    const int grp = b >> 7, bb = b & 127;
    __bf16* dst = grp ? vp1 : vp0;
    gemm_core<float, __bf16>(As, Bs, Vsr + grp * 2048, WvT + grp * 2048, bv, dst,
                             2048, 1024, 2048, 4096, 4096, 1,
                             (bb & 15) * 128, (bb >> 4) * 128, grp == 0 ? 1.0f : 0.0f);
  }
}

// Sum split-K partials -> final bf16 buffers. 2048 blocks x 256 thr x 8 elems.
// First half: kb = kp0+kp1 (bias already in kp0). Second half: vtb = vp0+vp1.
__global__ __launch_bounds__(256) void finalize2(
    const __bf16* __restrict__ kp0, const __bf16* __restrict__ kp1, __bf16* __restrict__ kb,
    const __bf16* __restrict__ vp0, const __bf16* __restrict__ vp1, __bf16* __restrict__ vtb) {
  int i = blockIdx.x * 256 + threadIdx.x;
  const __bf16 *a, *b;
  __bf16* d;
  int j;
  if (i < 262144) { a = kp0; b = kp1; d = kb;  j = i; }
  else            { a = vp0; b = vp1; d = vtb; j = i - 262144; }
  bf16x8 x = ld16v(a + (size_t)j * 8);
  bf16x8 y = ld16v(b + (size_t)j * 8);
  V16 o;
#pragma unroll
  for (int t = 0; t < 8; t++) o.v[t] = (__bf16)((float)x[t] + (float)y[t]);
  *(uint4*)(d + (size_t)j * 8) = o.u;
}

__global__ __launch_bounds__(256) void gemm_b_f(const __bf16* __restrict__ A,
                                                const __bf16* __restrict__ Bt,
                                                const float* __restrict__ bias,
                                                float* __restrict__ C,
                                                int M, int N, int K, int lda, int trans) {
  __shared__ __align__(16) __bf16 As[128 * 32];
  __shared__ __align__(16) __bf16 Bs[128 * 32];
  gemm_core<__bf16, float>(As, Bs, A, Bt, bias, C, M, N, K, lda, K, trans,
                           blockIdx.x * 128, blockIdx.y * 128, 1.0f);
}

// -------- flash attention --------
// QBLK=128, 8 waves x 16 q-rows, grid 64x8 = 512 blocks (2/CU, 16 w/CU).
// Double-buffered K/V tiles + one-tile prefetch, counted vmcnt (T4).
// NOTE: o may alias q (in-place): each block reads its q slice into regs
// before any store, and read/write slices are block-disjoint -> safe.
// (q/o deliberately NOT __restrict__.)
__global__ __launch_bounds__(512, 4) void attn_k(const __bf16* q,
                                                 const __bf16* __restrict__ k,
                                                 const __bf16* __restrict__ vt,
                                                 __bf16* o) {
  __shared__ __align__(16) __bf16 ks[2][64 * 128];   // K tile [s][e], swizzled chunks
  __shared__ __align__(16) __bf16 vs[2][128 * 64];   // V^T tile [e][s], swizzled chunks
  __shared__ __align__(16) __bf16 ps[128 * 64];      // P tile [q][s], swizzled chunks
  const int tid = threadIdx.x, lane = tid & 63, wave = tid >> 6;
  const int g = lane >> 4, l16 = lane & 15;
  const int h = blockIdx.y, q0 = blockIdx.x * 128;

  const __bf16* kbase = k + (size_t)h * 128;
  const __bf16* vbase = vt + (size_t)(h * 128) * 2048;

  bf16x8 qf[4];                    // Q rows q0+wave*16+l16 (scale pre-folded)
#pragma unroll
  for (int kk = 0; kk < 4; kk++)
    qf[kk] = ld16v(q + (size_t)(q0 + wave * 16 + l16) * 1024 + h * 128 + kk * 32 + g * 8);

  f32x4 accO[8] = {};
  float m_i[4], l_i[4];
#pragma unroll
  for (int r = 0; r < 4; r++) { m_i[r] = -1e30f; l_i[r] = 0.f; }

  // prologue: stage tile 0 into buf 0 (4 DMA issues/wave)
  {
#pragma unroll
    for (int i = 0; i < 2; i++) {
      int c = wave * 128 + i * 64 + lane;
      int row = c >> 4, gc = (c & 15) ^ (row & 7);
      dma16(kbase + (size_t)row * 1024 + gc * 8, &ks[0][(wave * 128 + i * 64) * 8]);
    }
#pragma unroll
    for (int i = 0; i < 2; i++) {
      int c = wave * 128 + i * 64 + lane;
      int row = c >> 3, cc = (c & 7) ^ (row & 7);
      dma16(vbase + (size_t)row * 2048 + cc * 8, &vs[0][(wave * 128 + i * 64) * 8]);
    }
  }

  for (int t = 0; t < 32; t++) {
    const int cur = t & 1;
    // (A) all waves done reading buf^1 (prev tile's compute) -> safe to DMA
    asm volatile("s_waitcnt lgkmcnt(0)" ::: "memory");
    __builtin_amdgcn_s_barrier();
    __builtin_amdgcn_sched_barrier(0);
    {                               // prefetch tile t+1 into buf^1 (wraps at end)
      const int sn = ((t + 1) & 31) * 64;
#pragma unroll
      for (int i = 0; i < 2; i++) {
        int c = wave * 128 + i * 64 + lane;
        int row = c >> 4, gc = (c & 15) ^ (row & 7);
        dma16(kbase + (size_t)(sn + row) * 1024 + gc * 8,
              &ks[cur ^ 1][(wave * 128 + i * 64) * 8]);
      }
#pragma unroll
      for (int i = 0; i < 2; i++) {
        int c = wave * 128 + i * 64 + lane;
        int row = c >> 3, cc = (c & 7) ^ (row & 7);
        dma16(vbase + (size_t)row * 2048 + sn + cc * 8,
              &vs[cur ^ 1][(wave * 128 + i * 64) * 8]);
      }
    }
    // (B) tile t staged by ALL waves (own vmcnt(4) + barrier); prefetch stays
    // in flight across the barrier (counted vmcnt, never 0 in-loop).
    asm volatile("s_waitcnt vmcnt(4)" ::: "memory");
    __builtin_amdgcn_s_barrier();
    __builtin_amdgcn_sched_barrier(0);

    f32x4 sc[4] = {};
    __builtin_amdgcn_s_setprio(1);
#pragma unroll
    for (int kk = 0; kk < 4; kk++) {  // QK^T, contract e=128
      bf16x8 kf[4];
#pragma unroll
      for (int nf = 0; nf < 4; nf++) {
        int row = nf * 16 + l16;
        kf[nf] = ld16v(&ks[cur][(row * 16 + ((kk * 4 + g) ^ (row & 7))) * 8]);
      }
#pragma unroll
      for (int nf = 0; nf < 4; nf++)
        sc[nf] = __builtin_amdgcn_mfma_f32_16x16x32_bf16(qf[kk], kf[nf], sc[nf], 0, 0, 0);
    }
    __builtin_amdgcn_s_setprio(0);

    // online softmax, base-2 domain; row g*4+r lives in the 16 lanes of group g
#pragma unroll
    for (int r = 0; r < 4; r++) {
      float mx = fmaxf(fmaxf(sc[0][r], sc[1][r]), fmaxf(sc[2][r], sc[3][r]));
#pragma unroll
      for (int off = 1; off < 16; off <<= 1) mx = fmaxf(mx, __shfl_xor(mx, off));
      float mn = fmaxf(m_i[r], mx);
      float alpha = exp2_fast(m_i[r] - mn);
      float rs = 0.f;
#pragma unroll
      for (int nf = 0; nf < 4; nf++) {
        float p = exp2_fast(sc[nf][r] - mn);
        sc[nf][r] = p;
        rs += p;
      }
#pragma unroll
      for (int off = 1; off < 16; off <<= 1) rs += __shfl_xor(rs, off);
      m_i[r] = mn;
      l_i[r] = l_i[r] * alpha + rs;
#pragma unroll
      for (int ef = 0; ef < 8; ef++) accO[ef][r] *= alpha;
    }

    // P write: wave-private rows, swizzled chunks; same-wave DS order suffices
#pragma unroll
    for (int nf = 0; nf < 4; nf++)
#pragma unroll
      for (int r = 0; r < 4; r++) {
        int prow = wave * 16 + g * 4 + r;
        int cc = nf * 2 + (l16 >> 3);
        ps[(prow * 8 + (cc ^ (prow & 7))) * 8 + (l16 & 7)] = (__bf16)sc[nf][r];
      }

    __builtin_amdgcn_s_setprio(1);
#pragma unroll
    for (int kk = 0; kk < 2; kk++) {   // PV, contract s=64
      int prow = wave * 16 + l16;
      bf16x8 pf = ld16v(&ps[(prow * 8 + ((kk * 4 + g) ^ (prow & 7))) * 8]);
#pragma unroll
      for (int ef = 0; ef < 8; ef++) {
        int vrow = ef * 16 + l16;
        bf16x8 vf = ld16v(&vs[cur][(vrow * 8 + ((kk * 4 + g) ^ (vrow & 7))) * 8]);
        accO[ef] = __builtin_amdgcn_mfma_f32_16x16x32_bf16(pf, vf, accO[ef], 0, 0, 0);
      }
    }
    __builtin_amdgcn_s_setprio(0);
  }

  float inv[4];
#pragma unroll
  for (int r = 0; r < 4; r++) inv[r] = 1.0f / l_i[r];
#pragma unroll
  for (int ef = 0; ef < 8; ef++)
#pragma unroll
    for (int r = 0; r < 4; r++) {
      int row = q0 + wave * 16 + g * 4 + r;
      o[(size_t)row * 1024 + h * 128 + ef * 16 + l16] = (__bf16)(accO[ef][r] * inv[r]);
    }
}

extern "C" void kernel_launch(void* const* d_in, const int* in_sizes, int n_in,
                              void* d_out, int out_size, void* d_ws, size_t ws_size,
                              hipStream_t stream) {
  const float* Q   = (const float*)d_in[0];
  const float* Ksr = (const float*)d_in[1];
  const float* Vsr = (const float*)d_in[2];
  const float* Wq  = (const float*)d_in[3];
  const float* bq  = (const float*)d_in[4];
  const float* Wk  = (const float*)d_in[5];
  const float* bk  = (const float*)d_in[6];
  const float* Wv  = (const float*)d_in[7];
  const float* bv  = (const float*)d_in[8];
  const float* Wo  = (const float*)d_in[9];
  const float* bo  = (const float*)d_in[10];
  __bf16* ws = (__bf16*)d_ws;
  const size_t MB = 1024 * 1024;
  __bf16* qb  = ws;             // [8192,1024] q; attn overwrites in-place with output
  __bf16* kb  = ws + 8  * MB;   // [2048,1024]
  __bf16* vtb = ws + 10 * MB;   // [1024,2048] = v^T
  __bf16* kp0 = ws + 12 * MB;   // [2048,1024] K-proj partial (K-half 0, +bias)
  __bf16* kp1 = ws + 14 * MB;   // [2048,1024] K-proj partial (K-half 1)
  __bf16* vp0 = ws + 16 * MB;   // [1024,2048] V-proj^T partial (+bias)
  __bf16* vp1 = ws + 18 * MB;   // [1024,2048] V-proj^T partial
  __bf16* WqT = ws + 20 * MB;   // [1024,1024]
  __bf16* WkT = ws + 21 * MB;   // [1024,4096]
  __bf16* WvT = ws + 25 * MB;   // [1024,4096]
  __bf16* WoT = ws + 29 * MB;   // [4096,1024]

  // 1/sqrt(512) * log2(e): softmax computed as 2^x in attn_k
  const float qscale = 0.044194173824159216f * 1.4426950408889634f;

  transpose_k<<<dim3(32, 32),  256, 0, stream>>>(Wq, WqT, 1024, 1024, qscale);
  transpose_k<<<dim3(32, 128), 256, 0, stream>>>(Wk, WkT, 4096, 1024, 1.0f);
  transpose_k<<<dim3(32, 128), 256, 0, stream>>>(Wv, WvT, 4096, 1024, 1.0f);
  transpose_k<<<dim3(128, 32), 256, 0, stream>>>(Wo, WoT, 1024, 4096, 1.0f);

  gemm_qkv<<<dim3(768), 256, 0, stream>>>(Q, WqT, bq, qb, qscale,
                                          Ksr, WkT, bk, kp0, kp1,
                                          Vsr, WvT, bv, vp0, vp1);
  finalize2<<<dim3(2048), 256, 0, stream>>>(kp0, kp1, kb, vp0, vp1, vtb);
  attn_k<<<dim3(64, 8), 512, 0, stream>>>(qb, kb, vtb, qb);
  gemm_b_f<<<dim3(64, 32), 256, 0, stream>>>(qb, WoT, bo, (float*)d_out, 8192, 4096, 1024, 1024, 0);
}

// Round 6
// 622.176 us; speedup vs baseline: 1.0646x; 1.0232x over previous
//
#include <hip/hip_runtime.h>
#include <hip/hip_bf16.h>

// ReprogrammingLayer: q=QWq+bq; k=KsWk+bk; v=VsVv+bv (8 heads, E=128);
// A=softmax(qk^T/sqrt(512)); out=(Av)Wo+bo.
// I/O FP32 (reference dtypes); internal bf16 MFMA + fp32 accum (2% threshold).
// scale*log2(e) is folded into Wq/bq so attention softmax runs in base-2.
//
// Round-6: pipelined fp32-A GEMM core (gemm_qkv). Round-5 counters showed
// ~6500 cy/block-iter vs ~240 cy MFMA floor with nothing saturated: the
// fp32-A path serialized TWO global-load latencies per k-iter (A-reg wait +
// B dma drain at __syncthreads). Fix = attn_k's proven counted-vmcnt
// pipeline: A(t+1) regs + B(t+1) dma prefetched during t, compute barrier
// waits vmcnt(6) (B(t) only; prefetch stays in flight), NO sched_barrier
// (round-4's regression was sched_barrier(0) order-pinning, m141 pattern).
//
// ws layout (bf16 elems, 33M = 66MB):
//   qb[8M]@0 (q; attn writes output IN-PLACE) | kb[2M]@8M | vtb[2M]@10M
//   kp0[2M]@12M | kp1[2M]@14M | vp0[2M]@16M | vp1[2M]@18M   (split-K partials)
//   WqT[1M]@20M | WkT[4M]@21M | WvT[4M]@25M | WoT[4M]@29M

typedef __bf16 bf16x8 __attribute__((ext_vector_type(8)));
typedef float  f32x4  __attribute__((ext_vector_type(4)));

union V16 { uint4 u; bf16x8 v; };
__device__ __forceinline__ bf16x8 ld16v(const void* p) {
  V16 t; t.u = *(const uint4*)p; return t.v;
}
__device__ __forceinline__ uint4 pack8(float4 a, float4 b) {
  V16 t;
  t.v[0] = (__bf16)a.x; t.v[1] = (__bf16)a.y; t.v[2] = (__bf16)a.z; t.v[3] = (__bf16)a.w;
  t.v[4] = (__bf16)b.x; t.v[5] = (__bf16)b.y; t.v[6] = (__bf16)b.z; t.v[7] = (__bf16)b.w;
  return t.u;
}
// async global->LDS DMA, 16B/lane; LDS dest = wave-uniform base + lane*16
__device__ __forceinline__ void dma16(const void* g, void* l) {
  __builtin_amdgcn_global_load_lds(
      (const __attribute__((address_space(1))) unsigned int*)g,
      (__attribute__((address_space(3))) unsigned int*)l, 16, 0, 0);
}
// raw v_exp_f32 (D = 2^S0); s_nop covers the trans->use wait state.
__device__ __forceinline__ float exp2_fast(float x) {
  float r;
  asm("v_exp_f32 %0, %1\n\ts_nop 1" : "=v"(r) : "v"(x));
  return r;
}
// XOR-swizzled 16B-chunk index for a 128x32 bf16 tile (4 chunks/row).
__device__ __forceinline__ int chunk_of(int row, int gc) {
  return row * 4 + (gc ^ ((row >> 1) & 3));
}

// -------- weight transpose+convert+scale: W[K][N] fp32 -> Wt[N][K] bf16 ----
__global__ __launch_bounds__(256) void transpose_k(const float* __restrict__ W,
                                                   __bf16* __restrict__ Wt, int K, int N,
                                                   float scale) {
  __shared__ __bf16 t[32][33];
  int tx = threadIdx.x & 31, ty = threadIdx.x >> 5;
  int n0 = blockIdx.x * 32, k0 = blockIdx.y * 32;
#pragma unroll
  for (int r = 0; r < 32; r += 8)
    t[ty + r][tx] = (__bf16)(W[(size_t)(k0 + ty + r) * N + n0 + tx] * scale);
  __syncthreads();
#pragma unroll
  for (int r = 0; r < 32; r += 8) Wt[(size_t)(n0 + ty + r) * K + k0 + tx] = t[tx][ty + r];
}

// shared epilogue: acc -> C (+bias)
template <typename CT>
__device__ __forceinline__ void gemm_epilogue(f32x4 (&acc)[4][4],
                                              const float* __restrict__ bias,
                                              CT* __restrict__ C,
                                              int M, int N, int trans,
                                              int m0, int n0, float bscale,
                                              int wr, int wc, int g, int l16) {
#pragma unroll
  for (int nf = 0; nf < 4; nf++) {
    int col = n0 + wc * 64 + nf * 16 + l16;
    float bv = bias[col] * bscale;
#pragma unroll
    for (int mf = 0; mf < 4; mf++) {
      int rowb = m0 + wr * 64 + mf * 16 + g * 4;
      if constexpr (sizeof(CT) == 2) {
        if (trans) {
          union { __bf16 h[4]; uint2 u; } pk;
#pragma unroll
          for (int r = 0; r < 4; r++) pk.h[r] = (__bf16)(acc[mf][nf][r] + bv);
          *(uint2*)&((__bf16*)C)[(size_t)col * M + rowb] = pk.u;   // C^T[n][m]
        } else {
#pragma unroll
          for (int r = 0; r < 4; r++)
            ((__bf16*)C)[(size_t)(rowb + r) * N + col] = (__bf16)(acc[mf][nf][r] + bv);
        }
      } else {
#pragma unroll
        for (int r = 0; r < 4; r++)
          ((float*)C)[(size_t)(rowb + r) * N + col] = acc[mf][nf][r] + bv;
      }
    }
  }
}

// -------- pipelined fp32-A GEMM core: C = A[M,K]fp32 @ Bt[N,K]^T + b ------
// 128x128 tile, BK=32, 4 waves 2x2. A: global->regs (prefetched 1 iter
// ahead) ->pack bf16->ds_write into single As. B: dma16 into double Bs.
// Counted vmcnt: compute barrier waits vmcnt(6)+lgkm(0) => B(t) landed,
// A(t+1)x4 + B(t+1)x2 stay in flight. No sched_barrier (m141).
template <typename CT>
__device__ __forceinline__ void gemm_core_f32(__bf16* As, __bf16* Bs0, __bf16* Bs1,
                                              const float* __restrict__ A,
                                              const __bf16* __restrict__ Bt,
                                              const float* __restrict__ bias,
                                              CT* __restrict__ C,
                                              int M, int N, int K, int lda, int ldb, int trans,
                                              int m0, int n0, float bscale) {
  const int tid = threadIdx.x;
  const int lane = tid & 63, wave = tid >> 6;
  const int g = lane >> 4, l16 = lane & 15;
  const int wr = wave >> 1, wc = wave & 1;
  int aoff[4], boff[4];
#pragma unroll
  for (int mf = 0; mf < 4; mf++) aoff[mf] = chunk_of(wr * 64 + mf * 16 + l16, g) * 8;
#pragma unroll
  for (int nf = 0; nf < 4; nf++) boff[nf] = chunk_of(wc * 64 + nf * 16 + l16, g) * 8;

  // A reg-stage geometry (2 chunks/thread)
  const int p0 = tid, p1 = tid + 256;
  const int ar0 = p0 >> 2, ag0 = (p0 & 3) ^ ((ar0 >> 1) & 3);
  const int ar1 = p1 >> 2, ag1 = (p1 & 3) ^ ((ar1 >> 1) & 3);
  const float* aptr0 = A + (size_t)(m0 + ar0) * lda + ag0 * 8;
  const float* aptr1 = A + (size_t)(m0 + ar1) * lda + ag1 * 8;

  f32x4 acc[4][4] = {};
  float4 a0l, a0h, a1l, a1h;
  // prologue: A(0) regs + B(0) dma -> Bs0
  a0l = *(const float4*)aptr0; a0h = *(const float4*)(aptr0 + 4);
  a1l = *(const float4*)aptr1; a1h = *(const float4*)(aptr1 + 4);
#pragma unroll
  for (int rnd = 0; rnd < 2; rnd++) {
    int c = wave * 128 + rnd * 64 + lane;
    int row = c >> 2, gc = (c & 3) ^ ((row >> 1) & 3);
    dma16(Bt + (size_t)(n0 + row) * (size_t)ldb + gc * 8,
          Bs0 + (wave * 128 + rnd * 64) * 8);
  }

  const int T = K >> 5;
  for (int t = 0; t < T; t++) {
    __bf16* Bc = (t & 1) ? Bs1 : Bs0;
    __bf16* Bn = (t & 1) ? Bs0 : Bs1;
    const int kn = (t + 1 < T) ? (t + 1) * 32 : 0;  // wrap: redundant, uniform counts
    // (A) all waves done reading As/Bc of iter t-1 -> safe to overwrite
    asm volatile("s_waitcnt lgkmcnt(0)" ::: "memory");
    __builtin_amdgcn_s_barrier();
    // commit A(t) (regs loaded one iter ago; auto-wait is vmcnt(2))
    *(uint4*)(As + p0 * 8) = pack8(a0l, a0h);
    *(uint4*)(As + p1 * 8) = pack8(a1l, a1h);
    // prefetch A(t+1) regs + B(t+1) dma
    a0l = *(const float4*)(aptr0 + kn); a0h = *(const float4*)(aptr0 + kn + 4);
    a1l = *(const float4*)(aptr1 + kn); a1h = *(const float4*)(aptr1 + kn + 4);
#pragma unroll
    for (int rnd = 0; rnd < 2; rnd++) {
      int c = wave * 128 + rnd * 64 + lane;
      int row = c >> 2, gc = (c & 3) ^ ((row >> 1) & 3);
      dma16(Bt + (size_t)(n0 + row) * (size_t)ldb + kn + gc * 8,
            Bn + (wave * 128 + rnd * 64) * 8);
    }
    // (B) B(t) landed + own ds_writes done; 6 prefetch ops stay in flight
    asm volatile("s_waitcnt vmcnt(6) lgkmcnt(0)" ::: "memory");
    __builtin_amdgcn_s_barrier();

    bf16x8 af[4], bff[4];
#pragma unroll
    for (int mf = 0; mf < 4; mf++) af[mf]  = ld16v(As + aoff[mf]);
#pragma unroll
    for (int nf = 0; nf < 4; nf++) bff[nf] = ld16v(Bc + boff[nf]);
    __builtin_amdgcn_s_setprio(1);
#pragma unroll
    for (int mf = 0; mf < 4; mf++)
#pragma unroll
      for (int nf = 0; nf < 4; nf++)
        acc[mf][nf] = __builtin_amdgcn_mfma_f32_16x16x32_bf16(af[mf], bff[nf], acc[mf][nf], 0, 0, 0);
    __builtin_amdgcn_s_setprio(0);
  }
  gemm_epilogue(acc, bias, C, M, N, trans, m0, n0, bscale, wr, wc, g, l16);
}

// -------- simple bf16-A GEMM core (m97 2-barrier; relies on co-residency) --
template <typename CT>
__device__ __forceinline__ void gemm_core_b16(__bf16* As, __bf16* Bs,
                                              const __bf16* __restrict__ A,
                                              const __bf16* __restrict__ Bt,
                                              const float* __restrict__ bias,
                                              CT* __restrict__ C,
                                              int M, int N, int K, int lda, int ldb, int trans,
                                              int m0, int n0, float bscale) {
  const int tid = threadIdx.x;
  const int lane = tid & 63, wave = tid >> 6;
  const int g = lane >> 4, l16 = lane & 15;
  const int wr = wave >> 1, wc = wave & 1;
  int aoff[4], boff[4];
#pragma unroll
  for (int mf = 0; mf < 4; mf++) aoff[mf] = chunk_of(wr * 64 + mf * 16 + l16, g) * 8;
#pragma unroll
  for (int nf = 0; nf < 4; nf++) boff[nf] = chunk_of(wc * 64 + nf * 16 + l16, g) * 8;

  f32x4 acc[4][4] = {};
  for (int k0 = 0; k0 < K; k0 += 32) {
    __syncthreads();
#pragma unroll
    for (int rnd = 0; rnd < 2; rnd++) {
      int cstart = wave * 128 + rnd * 64;
      int p = cstart + lane;
      int row = p >> 2, gc = (p & 3) ^ ((row >> 1) & 3);
      dma16(A + (size_t)(m0 + row) * lda + k0 + gc * 8, As + (size_t)cstart * 8);
    }
#pragma unroll
    for (int rnd = 0; rnd < 2; rnd++) {
      int cstart = wave * 128 + rnd * 64;
      int p = cstart + lane;
      int row = p >> 2, gc = (p & 3) ^ ((row >> 1) & 3);
      dma16(Bt + (size_t)(n0 + row) * (size_t)ldb + k0 + gc * 8, Bs + (size_t)cstart * 8);
    }
    __syncthreads();
    bf16x8 af[4], bff[4];
#pragma unroll
    for (int mf = 0; mf < 4; mf++) af[mf]  = ld16v(As + aoff[mf]);
#pragma unroll
    for (int nf = 0; nf < 4; nf++) bff[nf] = ld16v(Bs + boff[nf]);
#pragma unroll
    for (int mf = 0; mf < 4; mf++)
#pragma unroll
      for (int nf = 0; nf < 4; nf++)
        acc[mf][nf] = __builtin_amdgcn_mfma_f32_16x16x32_bf16(af[mf], bff[nf], acc[mf][nf], 0, 0, 0);
  }
  gemm_epilogue(acc, bias, C, M, N, trans, m0, n0, bscale, wr, wc, g, l16);
}

// Merged QKV projection, 768 UNIFORM blocks (all 64 k-iters, 3/CU):
//   bid [0,256):   q = Q @ WqT + bq*qscale — TWO n-tiles per block
//   bid [256,512): k partials: split-K=2 over K=4096 (+bk in group 0)
//   bid [512,768): v partials, transposed output
__global__ __launch_bounds__(256) void gemm_qkv(
    const float* __restrict__ Q,   const __bf16* __restrict__ WqT, const float* __restrict__ bq, __bf16* __restrict__ qb, float qscale,
    const float* __restrict__ Ksr, const __bf16* __restrict__ WkT, const float* __restrict__ bk, __bf16* __restrict__ kp0, __bf16* __restrict__ kp1,
    const float* __restrict__ Vsr, const __bf16* __restrict__ WvT, const float* __restrict__ bv, __bf16* __restrict__ vp0, __bf16* __restrict__ vp1) {
  __shared__ __align__(16) __bf16 As[128 * 32];
  __shared__ __align__(16) __bf16 Bs[2][128 * 32];
  const int bid = blockIdx.x;
  if (bid < 256) {
    const int m0 = (bid & 63) * 128, n0 = (bid >> 6) * 256;
    gemm_core_f32<__bf16>(As, Bs[0], Bs[1], Q, WqT, bq, qb, 8192, 1024, 1024, 1024, 1024, 0,
                          m0, n0, qscale);
    gemm_core_f32<__bf16>(As, Bs[0], Bs[1], Q, WqT, bq, qb, 8192, 1024, 1024, 1024, 1024, 0,
                          m0, n0 + 128, qscale);
  } else if (bid < 512) {
    const int b = bid - 256;
    const int grp = b >> 7, bb = b & 127;          // grp: K-half
    __bf16* dst = grp ? kp1 : kp0;
    gemm_core_f32<__bf16>(As, Bs[0], Bs[1], Ksr + grp * 2048, WkT + grp * 2048, bk, dst,
                          2048, 1024, 2048, 4096, 4096, 0,
                          (bb & 15) * 128, (bb >> 4) * 128, grp == 0 ? 1.0f : 0.0f);
  } else {
    const int b = bid - 512;
    const int grp = b >> 7, bb = b & 127;
    __bf16* dst = grp ? vp1 : vp0;
    gemm_core_f32<__bf16>(As, Bs[0], Bs[1], Vsr + grp * 2048, WvT + grp * 2048, bv, dst,
                          2048, 1024, 2048, 4096, 4096, 1,
                          (bb & 15) * 128, (bb >> 4) * 128, grp == 0 ? 1.0f : 0.0f);
  }
}

// Sum split-K partials -> final bf16 buffers. 2048 blocks x 256 thr x 8 elems.
__global__ __launch_bounds__(256) void finalize2(
    const __bf16* __restrict__ kp0, const __bf16* __restrict__ kp1, __bf16* __restrict__ kb,
    const __bf16* __restrict__ vp0, const __bf16* __restrict__ vp1, __bf16* __restrict__ vtb) {
  int i = blockIdx.x * 256 + threadIdx.x;
  const __bf16 *a, *b;
  __bf16* d;
  int j;
  if (i < 262144) { a = kp0; b = kp1; d = kb;  j = i; }
  else            { a = vp0; b = vp1; d = vtb; j = i - 262144; }
  bf16x8 x = ld16v(a + (size_t)j * 8);
  bf16x8 y = ld16v(b + (size_t)j * 8);
  V16 o;
#pragma unroll
  for (int t = 0; t < 8; t++) o.v[t] = (__bf16)((float)x[t] + (float)y[t]);
  *(uint4*)(d + (size_t)j * 8) = o.u;
}

__global__ __launch_bounds__(256) void gemm_b_f(const __bf16* __restrict__ A,
                                                const __bf16* __restrict__ Bt,
                                                const float* __restrict__ bias,
                                                float* __restrict__ C,
                                                int M, int N, int K, int lda, int trans) {
  __shared__ __align__(16) __bf16 As[128 * 32];
  __shared__ __align__(16) __bf16 Bs[128 * 32];
  gemm_core_b16<float>(As, Bs, A, Bt, bias, C, M, N, K, lda, K, trans,
                       blockIdx.x * 128, blockIdx.y * 128, 1.0f);
}

// -------- flash attention --------
// QBLK=128, 8 waves x 16 q-rows, grid 64x8 = 512 blocks (2/CU, 16 w/CU).
// Double-buffered K/V tiles + one-tile prefetch, counted vmcnt (T4).
// NOTE: o may alias q (in-place): each block reads its q slice into regs
// before any store, and read/write slices are block-disjoint -> safe.
__global__ __launch_bounds__(512, 4) void attn_k(const __bf16* q,
                                                 const __bf16* __restrict__ k,
                                                 const __bf16* __restrict__ vt,
                                                 __bf16* o) {
  __shared__ __align__(16) __bf16 ks[2][64 * 128];   // K tile [s][e], swizzled chunks
  __shared__ __align__(16) __bf16 vs[2][128 * 64];   // V^T tile [e][s], swizzled chunks
  __shared__ __align__(16) __bf16 ps[128 * 64];      // P tile [q][s], swizzled chunks
  const int tid = threadIdx.x, lane = tid & 63, wave = tid >> 6;
  const int g = lane >> 4, l16 = lane & 15;
  const int h = blockIdx.y, q0 = blockIdx.x * 128;

  const __bf16* kbase = k + (size_t)h * 128;
  const __bf16* vbase = vt + (size_t)(h * 128) * 2048;

  bf16x8 qf[4];                    // Q rows q0+wave*16+l16 (scale pre-folded)
#pragma unroll
  for (int kk = 0; kk < 4; kk++)
    qf[kk] = ld16v(q + (size_t)(q0 + wave * 16 + l16) * 1024 + h * 128 + kk * 32 + g * 8);

  f32x4 accO[8] = {};
  float m_i[4], l_i[4];
#pragma unroll
  for (int r = 0; r < 4; r++) { m_i[r] = -1e30f; l_i[r] = 0.f; }

  // prologue: stage tile 0 into buf 0 (4 DMA issues/wave)
  {
#pragma unroll
    for (int i = 0; i < 2; i++) {
      int c = wave * 128 + i * 64 + lane;
      int row = c >> 4, gc = (c & 15) ^ (row & 7);
      dma16(kbase + (size_t)row * 1024 + gc * 8, &ks[0][(wave * 128 + i * 64) * 8]);
    }
#pragma unroll
    for (int i = 0; i < 2; i++) {
      int c = wave * 128 + i * 64 + lane;
      int row = c >> 3, cc = (c & 7) ^ (row & 7);
      dma16(vbase + (size_t)row * 2048 + cc * 8, &vs[0][(wave * 128 + i * 64) * 8]);
    }
  }

  for (int t = 0; t < 32; t++) {
    const int cur = t & 1;
    // (A) all waves done reading buf^1 (prev tile's compute) -> safe to DMA
    asm volatile("s_waitcnt lgkmcnt(0)" ::: "memory");
    __builtin_amdgcn_s_barrier();
    __builtin_amdgcn_sched_barrier(0);
    {                               // prefetch tile t+1 into buf^1 (wraps at end)
      const int sn = ((t + 1) & 31) * 64;
#pragma unroll
      for (int i = 0; i < 2; i++) {
        int c = wave * 128 + i * 64 + lane;
        int row = c >> 4, gc = (c & 15) ^ (row & 7);
        dma16(kbase + (size_t)(sn + row) * 1024 + gc * 8,
              &ks[cur ^ 1][(wave * 128 + i * 64) * 8]);
      }
#pragma unroll
      for (int i = 0; i < 2; i++) {
        int c = wave * 128 + i * 64 + lane;
        int row = c >> 3, cc = (c & 7) ^ (row & 7);
        dma16(vbase + (size_t)row * 2048 + sn + cc * 8,
              &vs[cur ^ 1][(wave * 128 + i * 64) * 8]);
      }
    }
    // (B) tile t staged by ALL waves (own vmcnt(4) + barrier); prefetch stays
    // in flight across the barrier (counted vmcnt, never 0 in-loop).
    asm volatile("s_waitcnt vmcnt(4)" ::: "memory");
    __builtin_amdgcn_s_barrier();
    __builtin_amdgcn_sched_barrier(0);

    f32x4 sc[4] = {};
    __builtin_amdgcn_s_setprio(1);
#pragma unroll
    for (int kk = 0; kk < 4; kk++) {  // QK^T, contract e=128
      bf16x8 kf[4];
#pragma unroll
      for (int nf = 0; nf < 4; nf++) {
        int row = nf * 16 + l16;
        kf[nf] = ld16v(&ks[cur][(row * 16 + ((kk * 4 + g) ^ (row & 7))) * 8]);
      }
#pragma unroll
      for (int nf = 0; nf < 4; nf++)
        sc[nf] = __builtin_amdgcn_mfma_f32_16x16x32_bf16(qf[kk], kf[nf], sc[nf], 0, 0, 0);
    }
    __builtin_amdgcn_s_setprio(0);

    // online softmax, base-2 domain; row g*4+r lives in the 16 lanes of group g
#pragma unroll
    for (int r = 0; r < 4; r++) {
      float mx = fmaxf(fmaxf(sc[0][r], sc[1][r]), fmaxf(sc[2][r], sc[3][r]));
#pragma unroll
      for (int off = 1; off < 16; off <<= 1) mx = fmaxf(mx, __shfl_xor(mx, off));
      float mn = fmaxf(m_i[r], mx);
      float alpha = exp2_fast(m_i[r] - mn);
      float rs = 0.f;
#pragma unroll
      for (int nf = 0; nf < 4; nf++) {
        float p = exp2_fast(sc[nf][r] - mn);
        sc[nf][r] = p;
        rs += p;
      }
#pragma unroll
      for (int off = 1; off < 16; off <<= 1) rs += __shfl_xor(rs, off);
      m_i[r] = mn;
      l_i[r] = l_i[r] * alpha + rs;
#pragma unroll
      for (int ef = 0; ef < 8; ef++) accO[ef][r] *= alpha;
    }

    // P write: wave-private rows, swizzled chunks; same-wave DS order suffices
#pragma unroll
    for (int nf = 0; nf < 4; nf++)
#pragma unroll
      for (int r = 0; r < 4; r++) {
        int prow = wave * 16 + g * 4 + r;
        int cc = nf * 2 + (l16 >> 3);
        ps[(prow * 8 + (cc ^ (prow & 7))) * 8 + (l16 & 7)] = (__bf16)sc[nf][r];
      }

    __builtin_amdgcn_s_setprio(1);
#pragma unroll
    for (int kk = 0; kk < 2; kk++) {   // PV, contract s=64
      int prow = wave * 16 + l16;
      bf16x8 pf = ld16v(&ps[(prow * 8 + ((kk * 4 + g) ^ (prow & 7))) * 8]);
#pragma unroll
      for (int ef = 0; ef < 8; ef++) {
        int vrow = ef * 16 + l16;
        bf16x8 vf = ld16v(&vs[cur][(vrow * 8 + ((kk * 4 + g) ^ (vrow & 7))) * 8]);
        accO[ef] = __builtin_amdgcn_mfma_f32_16x16x32_bf16(pf, vf, accO[ef], 0, 0, 0);
      }
    }
    __builtin_amdgcn_s_setprio(0);
  }

  float inv[4];
#pragma unroll
  for (int r = 0; r < 4; r++) inv[r] = 1.0f / l_i[r];
#pragma unroll
  for (int ef = 0; ef < 8; ef++)
#pragma unroll
    for (int r = 0; r < 4; r++) {
      int row = q0 + wave * 16 + g * 4 + r;
      o[(size_t)row * 1024 + h * 128 + ef * 16 + l16] = (__bf16)(accO[ef][r] * inv[r]);
    }
}

extern "C" void kernel_launch(void* const* d_in, const int* in_sizes, int n_in,
                              void* d_out, int out_size, void* d_ws, size_t ws_size,
                              hipStream_t stream) {
  const float* Q   = (const float*)d_in[0];
  const float* Ksr = (const float*)d_in[1];
  const float* Vsr = (const float*)d_in[2];
  const float* Wq  = (const float*)d_in[3];
  const float* bq  = (const float*)d_in[4];
  const float* Wk  = (const float*)d_in[5];
  const float* bk  = (const float*)d_in[6];
  const float* Wv  = (const float*)d_in[7];
  const float* bv  = (const float*)d_in[8];
  const float* Wo  = (const float*)d_in[9];
  const float* bo  = (const float*)d_in[10];
  __bf16* ws = (__bf16*)d_ws;
  const size_t MB = 1024 * 1024;
  __bf16* qb  = ws;             // [8192,1024] q; attn overwrites in-place with output
  __bf16* kb  = ws + 8  * MB;   // [2048,1024]
  __bf16* vtb = ws + 10 * MB;   // [1024,2048] = v^T
  __bf16* kp0 = ws + 12 * MB;   // [2048,1024] K-proj partial (K-half 0, +bias)
  __bf16* kp1 = ws + 14 * MB;   // [2048,1024] K-proj partial (K-half 1)
  __bf16* vp0 = ws + 16 * MB;   // [1024,2048] V-proj^T partial (+bias)
  __bf16* vp1 = ws + 18 * MB;   // [1024,2048] V-proj^T partial
  __bf16* WqT = ws + 20 * MB;   // [1024,1024]
  __bf16* WkT = ws + 21 * MB;   // [1024,4096]
  __bf16* WvT = ws + 25 * MB;   // [1024,4096]
  __bf16* WoT = ws + 29 * MB;   // [4096,1024]

  // 1/sqrt(512) * log2(e): softmax computed as 2^x in attn_k
  const float qscale = 0.044194173824159216f * 1.4426950408889634f;

  transpose_k<<<dim3(32, 32),  256, 0, stream>>>(Wq, WqT, 1024, 1024, qscale);
  transpose_k<<<dim3(32, 128), 256, 0, stream>>>(Wk, WkT, 4096, 1024, 1.0f);
  transpose_k<<<dim3(32, 128), 256, 0, stream>>>(Wv, WvT, 4096, 1024, 1.0f);
  transpose_k<<<dim3(128, 32), 256, 0, stream>>>(Wo, WoT, 1024, 4096, 1.0f);

  gemm_qkv<<<dim3(768), 256, 0, stream>>>(Q, WqT, bq, qb, qscale,
                                          Ksr, WkT, bk, kp0, kp1,
                                          Vsr, WvT, bv, vp0, vp1);
  finalize2<<<dim3(2048), 256, 0, stream>>>(kp0, kp1, kb, vp0, vp1, vtb);
  attn_k<<<dim3(64, 8), 512, 0, stream>>>(qb, kb, vtb, qb);
  gemm_b_f<<<dim3(64, 32), 256, 0, stream>>>(qb, WoT, bo, (float*)d_out, 8192, 4096, 1024, 1024, 0);
}